// Round 8
// baseline (310.409 us; speedup 1.0000x reference)
//
#include <hip/hip_runtime.h>

#define GENE_N  200000
#define BATCH   200000
#define EMBED   128
#define BM      32
#define THREADS 512
#define L2E     1.44269504088896340736f

typedef __attribute__((ext_vector_type(8))) short bf16x8;
typedef __attribute__((ext_vector_type(4))) float f32x4;

static __device__ __forceinline__ short f2bf(float f) {
    unsigned u = __builtin_bit_cast(unsigned, f);
    unsigned r = (u + 0x7fffu + ((u >> 16) & 1u)) >> 16;   // RNE
    return (short)(r & 0xffffu);
}
static __device__ __forceinline__ unsigned cvt_pk_bf16(float lo, float hi) {
    unsigned r;
    asm("v_cvt_pk_bf16_f32 %0, %1, %2" : "=v"(r) : "v"(lo), "v"(hi));
    return r;
}

// Barrier-free, LDS-free design: each (dir,jt) wave loads its MFMA
// A-fragments DIRECTLY from global (lane l: row l&15, f32 seg lgrp*8+s*32).
// The 8 waves of a block walk the same 32-row tiles -> 16KB tile is
// L1-resident, so the 8x redundancy is L1 traffic, not HBM. No barriers,
// no staging, no LDS: waves are fully independent (pure TLP latency hiding).
__global__ __launch_bounds__(THREADS, 4)
void hetagg_kernel(const float* __restrict__ gene_feat,
                   const float* __restrict__ cell_feat,
                   const float* __restrict__ gWf, const float* __restrict__ gbf,
                   const float* __restrict__ gWb, const float* __restrict__ gbb,
                   const float* __restrict__ cWf, const float* __restrict__ cbf,
                   const float* __restrict__ cWb, const float* __restrict__ cbb,
                   const int* __restrict__ c_ids, const int* __restrict__ p_ids,
                   const int* __restrict__ n_ids, float* __restrict__ out,
                   int gene_blocks, int cell_blocks)
{
    const int  bid     = blockIdx.x;
    const bool is_gene = (bid < gene_blocks);
    const int  tid     = threadIdx.x;
    const int  wid     = tid >> 6;
    const int  lane    = tid & 63;
    const int  lgrp    = lane >> 4;   // 0..3
    const int  lcol    = lane & 15;   // 0..15
    const int  dir     = wid >> 2;    // 0 fwd, 1 bwd
    const int  jt      = wid & 3;     // 16-wide j block
    const int  j       = jt * 16 + lcol;

    const float* feat = is_gene ? gene_feat : cell_feat;
    const float* W    = is_gene ? (dir ? gWb : gWf) : (dir ? cWb : cWf);
    const float* Bv   = is_gene ? (dir ? gbb : gbf) : (dir ? cbb : cbf);

    // exp2-domain gate scales folded into weights:
    //   a0 = -i*log2e (u=2^a0=e^-i); a1 = 2g*log2e (v=e^{2g}); a2 = -o*log2e (w=e^-o)
    const float gsc[3] = {-L2E, 2.0f * L2E, -L2E};
    const float b0 = -L2E * Bv[j];
    const float b1 = 2.0f * L2E * Bv[128 + j];
    const float b2 = -L2E * Bv[192 + j];

    // B fragments in registers for the whole kernel (pre-scaled)
    bf16x8 bfrag[3][4];
    {
        const int gate_base[3] = {0, 128, 192};
#pragma unroll
        for (int q = 0; q < 3; ++q) {
            const float* wrow = W + (size_t)(gate_base[q] + j) * EMBED;
            const float  sc   = gsc[q];
#pragma unroll
            for (int s = 0; s < 4; ++s) {
                const int k0 = s * 32 + lgrp * 8;
                float4 w0 = *(const float4*)(wrow + k0);
                float4 w1 = *(const float4*)(wrow + k0 + 4);
                bf16x8 b;
                b[0] = f2bf(sc * w0.x); b[1] = f2bf(sc * w0.y);
                b[2] = f2bf(sc * w0.z); b[3] = f2bf(sc * w0.w);
                b[4] = f2bf(sc * w1.x); b[5] = f2bf(sc * w1.y);
                b[6] = f2bf(sc * w1.z); b[7] = f2bf(sc * w1.w);
                bfrag[q][s] = b;
            }
        }
    }

    const int myb    = is_gene ? bid : (bid - gene_blocks);
    const int nb     = is_gene ? gene_blocks : cell_blocks;
    const int ntiles = is_gene ? (BATCH / BM) : (2 * BATCH / BM);
    const int nk     = (ntiles - myb + nb - 1) / nb;   // tiles for this block

#define FETCH_ID(grow) (is_gene ? c_ids[(grow)] \
                       : ((grow) < BATCH ? p_ids[(grow)] - GENE_N \
                                         : n_ids[(grow) - BATCH] - GENE_N))

    // Per-lane row ids for this wave's fragment rows (row = mt*16 + lcol).
    // idc = ids(tile k) ready; idn = ids(tile k+1) in flight.
    int idc[2], idn[2];
#pragma unroll
    for (int p = 0; p < 2; ++p) idc[p] = FETCH_ID(myb * BM + p * 16 + lcol);
#pragma unroll
    for (int p = 0; p < 2; ++p)
        idn[p] = (nk > 1) ? FETCH_ID((myb + nb) * BM + p * 16 + lcol) : 0;

    // One 16-row slab: direct-from-global A-fragments + MFMA + fused epilogue.
#define TILE_MT(RP, MT, BASE)                                                   \
    {                                                                           \
        f32x4 acc0 = {b0, b0, b0, b0};                                          \
        f32x4 acc1 = {b1, b1, b1, b1};                                          \
        f32x4 acc2 = {b2, b2, b2, b2};                                          \
        const f32x4* rv4 = (const f32x4*)(RP);                                  \
        _Pragma("unroll")                                                       \
        for (int s = 0; s < 4; ++s) {                                           \
            f32x4 lo = rv4[s * 8 + lgrp * 2];                                   \
            f32x4 hi = rv4[s * 8 + lgrp * 2 + 1];                               \
            int4 pk;                                                            \
            pk.x = (int)cvt_pk_bf16(lo[0], lo[1]);                              \
            pk.y = (int)cvt_pk_bf16(lo[2], lo[3]);                              \
            pk.z = (int)cvt_pk_bf16(hi[0], hi[1]);                              \
            pk.w = (int)cvt_pk_bf16(hi[2], hi[3]);                              \
            bf16x8 a = __builtin_bit_cast(bf16x8, pk);                          \
            acc0 = __builtin_amdgcn_mfma_f32_16x16x32_bf16(a, bfrag[0][s], acc0, 0, 0, 0); \
            acc1 = __builtin_amdgcn_mfma_f32_16x16x32_bf16(a, bfrag[1][s], acc1, 0, 0, 0); \
            acc2 = __builtin_amdgcn_mfma_f32_16x16x32_bf16(a, bfrag[2][s], acc2, 0, 0, 0); \
        }                                                                       \
        _Pragma("unroll")                                                       \
        for (int r = 0; r < 4; ++r) {                                           \
            const float a0 = acc0[r];                                           \
            const float a1 = fminf(acc1[r], 80.0f);                             \
            const float a2 = acc2[r];                                           \
            const float u  = __builtin_amdgcn_exp2f(a0);                        \
            const float v  = __builtin_amdgcn_exp2f(a1);                        \
            const float w  = __builtin_amdgcn_exp2f(a2);                        \
            const float tprod = (1.0f + u) * (v + 1.0f);                        \
            const float c  = (v - 1.0f) * __builtin_amdgcn_rcpf(tprod);         \
            const float c2 = c * c;                                             \
            const float num = c * (15.0f + c2);                                 \
            const float den = (15.0f + 6.0f * c2) * (1.0f + w);                 \
            const float h   = num * __builtin_amdgcn_rcpf(den);                 \
            const int row   = (BASE) + (MT) * 16 + lgrp * 4 + r;                \
            const size_t orow = (size_t)(is_gene ? row : (BATCH + row));        \
            out[orow * 128 + dir * 64 + j] = h;                                 \
        }                                                                       \
    }

    for (int k = 0; k < nk; ++k) {
        const int base = (myb + k * nb) * BM;
        // row pointers from ready ids (loaded >=1 tile ago)
        const float* rp0 = feat + (size_t)idc[0] * EMBED;
        const float* rp1 = feat + (size_t)idc[1] * EMBED;
        // rotate id pipeline; issue ids(k+2) to fly under this tile's compute
        idc[0] = idn[0]; idc[1] = idn[1];
        if (k + 2 < nk) {
            const int tb = (myb + (k + 2) * nb) * BM;
#pragma unroll
            for (int p = 0; p < 2; ++p) idn[p] = FETCH_ID(tb + p * 16 + lcol);
        }

        TILE_MT(rp0, 0, base);
        TILE_MT(rp1, 1, base);
    }

#undef TILE_MT
#undef FETCH_ID
}

extern "C" void kernel_launch(void* const* d_in, const int* in_sizes, int n_in,
                              void* d_out, int out_size, void* d_ws, size_t ws_size,
                              hipStream_t stream)
{
    const float* gene_feat = (const float*)d_in[0];
    const float* cell_feat = (const float*)d_in[1];
    const float* gWf = (const float*)d_in[2];
    const float* gbf = (const float*)d_in[3];
    const float* gWb = (const float*)d_in[4];
    const float* gbb = (const float*)d_in[5];
    const float* cWf = (const float*)d_in[6];
    const float* cbf = (const float*)d_in[7];
    const float* cWb = (const float*)d_in[8];
    const float* cbb = (const float*)d_in[9];
    const int* c_ids = (const int*)d_in[10];
    const int* p_ids = (const int*)d_in[11];
    const int* n_ids = (const int*)d_in[12];
    float* out = (float*)d_out;

    const int gene_blocks = 171;   // 6250 tiles of 32 rows -> 36-37 tiles/block
    const int cell_blocks = 341;   // 12500 tiles           -> 36-37 tiles/block
    dim3 grid(gene_blocks + cell_blocks);   // 512 = 2 blocks/CU, one round
    dim3 block(THREADS);
    hipLaunchKernelGGL(hetagg_kernel, grid, block, 0, stream,
                       gene_feat, cell_feat, gWf, gbf, gWb, gbb,
                       cWf, cbf, cWb, cbb, c_ids, p_ids, n_ids, out,
                       gene_blocks, cell_blocks);
}

// Round 9
// 182.695 us; speedup vs baseline: 1.6991x; 1.6991x over previous
//
#include <hip/hip_runtime.h>

#define GENE_N  200000
#define BATCH   200000
#define EMBED   128
#define BM      32
#define THREADS 256
#define LDS_STRIDE 136   // bf16 elems per LDS row: 128 + 8 pad
#define L2E     1.44269504088896340736f

typedef __attribute__((ext_vector_type(8))) short bf16x8;
typedef __attribute__((ext_vector_type(4))) float f32x4;

static __device__ __forceinline__ short f2bf(float f) {
    unsigned u = __builtin_bit_cast(unsigned, f);
    unsigned r = (u + 0x7fffu + ((u >> 16) & 1u)) >> 16;   // RNE
    return (short)(r & 0xffffu);
}
static __device__ __forceinline__ unsigned cvt_pk_bf16(float lo, float hi) {
    unsigned r;
    asm("v_cvt_pk_bf16_f32 %0, %1, %2" : "=v"(r) : "v"(lo), "v"(hi));
    return r;
}

// r9 structure: 256-thread blocks (4 waves), ONE direction per block.
//  - r6's proven dataflow (LDS staging + register row-prefetch) kept intact
//  - 4 independent 4-wave barrier groups per CU (vs 2x 8-wave): convoys are
//    half as wide and 4 groups interleave to fill each other's stalls
//  - next-tile gathers issued BEFORE the lgkm-drain+barrier (fly during wait)
//  - fwd/bwd blocks re-gather the same rows: redundancy is L2/L3-served
__global__ __launch_bounds__(THREADS, 4)   // cap 128 regs, 4 blocks/CU
void hetagg_kernel(const float* __restrict__ gene_feat,
                   const float* __restrict__ cell_feat,
                   const float* __restrict__ gWf, const float* __restrict__ gbf,
                   const float* __restrict__ gWb, const float* __restrict__ gbb,
                   const float* __restrict__ cWf, const float* __restrict__ cbf,
                   const float* __restrict__ cWb, const float* __restrict__ cbb,
                   const int* __restrict__ c_ids, const int* __restrict__ p_ids,
                   const int* __restrict__ n_ids, float* __restrict__ out,
                   int gene_blocks, int cell_blocks)
{
    __shared__ short A_lds[2][BM * LDS_STRIDE];

    const int bid = blockIdx.x;
    // decode (stream, dir): [gene-fwd | gene-bwd | cell-fwd | cell-bwd]
    const bool is_gene = (bid < 2 * gene_blocks);
    int dir, myb, nb, ntiles;
    if (is_gene) {
        dir = (bid >= gene_blocks);
        myb = bid - dir * gene_blocks;
        nb  = gene_blocks;
        ntiles = BATCH / BM;
    } else {
        const int b2 = bid - 2 * gene_blocks;
        dir = (b2 >= cell_blocks);
        myb = b2 - dir * cell_blocks;
        nb  = cell_blocks;
        ntiles = 2 * BATCH / BM;
    }

    const int tid  = threadIdx.x;
    const int wid  = tid >> 6;        // 0..3 = jt
    const int lane = tid & 63;
    const int lgrp = lane >> 4;       // 0..3
    const int lcol = lane & 15;       // 0..15
    const int j    = wid * 16 + lcol; // output col within direction [0,64)

    const float* feat = is_gene ? gene_feat : cell_feat;
    const float* W    = is_gene ? (dir ? gWb : gWf) : (dir ? cWb : cWf);
    const float* Bv   = is_gene ? (dir ? gbb : gbf) : (dir ? cbb : cbf);

    // exp2-domain gate scales folded into weights:
    //   a0 = -i*log2e (u=2^a0=e^-i); a1 = 2g*log2e (v=e^{2g}); a2 = -o*log2e (w=e^-o)
    const float gsc[3] = {-L2E, 2.0f * L2E, -L2E};
    const float b0 = -L2E * Bv[j];
    const float b1 = 2.0f * L2E * Bv[128 + j];
    const float b2 = -L2E * Bv[192 + j];

    // B fragments in registers for the whole kernel (pre-scaled)
    bf16x8 bfrag[3][4];
    {
        const int gate_base[3] = {0, 128, 192};
#pragma unroll
        for (int q = 0; q < 3; ++q) {
            const float* wrow = W + (size_t)(gate_base[q] + j) * EMBED;
            const float  sc   = gsc[q];
#pragma unroll
            for (int s = 0; s < 4; ++s) {
                const int k0 = s * 32 + lgrp * 8;
                float4 w0 = *(const float4*)(wrow + k0);
                float4 w1 = *(const float4*)(wrow + k0 + 4);
                bf16x8 b;
                b[0] = f2bf(sc * w0.x); b[1] = f2bf(sc * w0.y);
                b[2] = f2bf(sc * w0.z); b[3] = f2bf(sc * w0.w);
                b[4] = f2bf(sc * w1.x); b[5] = f2bf(sc * w1.y);
                b[6] = f2bf(sc * w1.z); b[7] = f2bf(sc * w1.w);
                bfrag[q][s] = b;
            }
        }
    }

    const int nk = (ntiles - myb + nb - 1) / nb;   // tiles for this block

    const int r0 = tid >> 5;   // 0..7 (staging row group)
    const int cc = tid & 31;   // float4 col within row

#define FETCH_ID(grow) (is_gene ? c_ids[(grow)] \
                       : ((grow) < BATCH ? p_ids[(grow)] - GENE_N \
                                         : n_ids[(grow) - BATCH] - GENE_N))

    // ---- prologue: rows(0) in flight, ids(1) ready ----
    float4 rv[4];
    int    idn[4];
    {
        int id0[4];
#pragma unroll
        for (int p = 0; p < 4; ++p) id0[p] = FETCH_ID(myb * BM + r0 + p * 8);
#pragma unroll
        for (int p = 0; p < 4; ++p)
            rv[p] = ((const float4*)(feat + (size_t)id0[p] * EMBED))[cc];
#pragma unroll
        for (int p = 0; p < 4; ++p)
            idn[p] = (nk > 1) ? FETCH_ID((myb + nb) * BM + r0 + p * 8) : 0;
    }

    int pb = 0;   // LDS buffer parity
    for (int k = 0; k < nk; ++k, pb ^= 1) {
        const int base = (myb + k * nb) * BM;
        short* buf = A_lds[pb];

        // ---- stage rows of tile k: cvt_pk f32->bf16 -> LDS ----
#pragma unroll
        for (int p = 0; p < 4; ++p) {
            int2 sv;
            sv.x = (int)cvt_pk_bf16(rv[p].x, rv[p].y);
            sv.y = (int)cvt_pk_bf16(rv[p].z, rv[p].w);
            *(int2*)&buf[(r0 + p * 8) * LDS_STRIDE + cc * 4] = sv;
        }
        // ---- issue tile k+1's gathers BEFORE the barrier (WAR on rv is
        // resolved: staging already consumed rv; loads fly during barrier
        // wait + the whole compute phase) ----
        if (k + 1 < nk) {
#pragma unroll
            for (int p = 0; p < 4; ++p)
                rv[p] = ((const float4*)(feat + (size_t)idn[p] * EMBED))[cc];
        }
        asm volatile("s_waitcnt lgkmcnt(0)" ::: "memory");
        __builtin_amdgcn_s_barrier();
        // double-buffer discipline: writes to buf[pb] can only race reads of
        // buf[pb] from iteration k-2; those reads precede barrier(k-1) in
        // every wave's program order, and we are past barrier(k). Safe.

        if (k + 2 < nk) {
            const int tb = (myb + (k + 2) * nb) * BM;
#pragma unroll
            for (int p = 0; p < 4; ++p) idn[p] = FETCH_ID(tb + r0 + p * 8);
        }

        // ---- MFMA + fused epilogue, one 16-row slab at a time ----
#pragma unroll
        for (int mt = 0; mt < 2; ++mt) {
            f32x4 acc0 = {b0, b0, b0, b0};
            f32x4 acc1 = {b1, b1, b1, b1};
            f32x4 acc2 = {b2, b2, b2, b2};
            const int m = mt * 16 + lcol;
#pragma unroll
            for (int s = 0; s < 4; ++s) {
                bf16x8 a = *(const bf16x8*)&buf[m * LDS_STRIDE + s * 32 + lgrp * 8];
                acc0 = __builtin_amdgcn_mfma_f32_16x16x32_bf16(a, bfrag[0][s], acc0, 0, 0, 0);
                acc1 = __builtin_amdgcn_mfma_f32_16x16x32_bf16(a, bfrag[1][s], acc1, 0, 0, 0);
                acc2 = __builtin_amdgcn_mfma_f32_16x16x32_bf16(a, bfrag[2][s], acc2, 0, 0, 0);
            }
            // epilogue: h = sigma(o)*tanh(sigma(i)*tanh(g)), exp2 domain
            // u=2^a0, v=2^a1, w=2^a2; c=(v-1)*rcp((1+u)(v+1));
            // tanh(c) ~= c(15+c^2)/(15+6c^2); h = c(15+c^2)*rcp((15+6c^2)(1+w))
#pragma unroll
            for (int r = 0; r < 4; ++r) {
                const float a0 = acc0[r];
                const float a1 = fminf(acc1[r], 80.0f);  // keep v finite
                const float a2 = acc2[r];
                const float u  = __builtin_amdgcn_exp2f(a0);
                const float v  = __builtin_amdgcn_exp2f(a1);
                const float w  = __builtin_amdgcn_exp2f(a2);
                const float tprod = (1.0f + u) * (v + 1.0f);
                const float c  = (v - 1.0f) * __builtin_amdgcn_rcpf(tprod);
                const float c2 = c * c;
                const float num = c * (15.0f + c2);
                const float den = (15.0f + 6.0f * c2) * (1.0f + w);
                const float h   = num * __builtin_amdgcn_rcpf(den);
                const int row   = base + mt * 16 + lgrp * 4 + r;
                const size_t orow = (size_t)(is_gene ? row : (BATCH + row));
                out[orow * 128 + dir * 64 + j] = h;
            }
        }
    }
#undef FETCH_ID
}

extern "C" void kernel_launch(void* const* d_in, const int* in_sizes, int n_in,
                              void* d_out, int out_size, void* d_ws, size_t ws_size,
                              hipStream_t stream)
{
    const float* gene_feat = (const float*)d_in[0];
    const float* cell_feat = (const float*)d_in[1];
    const float* gWf = (const float*)d_in[2];
    const float* gbf = (const float*)d_in[3];
    const float* gWb = (const float*)d_in[4];
    const float* gbb = (const float*)d_in[5];
    const float* cWf = (const float*)d_in[6];
    const float* cbf = (const float*)d_in[7];
    const float* cWb = (const float*)d_in[8];
    const float* cbb = (const float*)d_in[9];
    const int* c_ids = (const int*)d_in[10];
    const int* p_ids = (const int*)d_in[11];
    const int* n_ids = (const int*)d_in[12];
    float* out = (float*)d_out;

    const int gene_blocks = 171;   // x2 dirs; 6250 tiles -> 36-37 tiles/block
    const int cell_blocks = 341;   // x2 dirs; 12500 tiles -> 36-37 tiles/block
    dim3 grid(2 * gene_blocks + 2 * cell_blocks);   // 1024 = 4 blocks/CU
    dim3 block(THREADS);
    hipLaunchKernelGGL(hetagg_kernel, grid, block, 0, stream,
                       gene_feat, cell_feat, gWf, gbf, gWb, gbb,
                       cWf, cbf, cWb, cbb, c_ids, p_ids, n_ids, out,
                       gene_blocks, cell_blocks);
}

// Round 10
// 180.309 us; speedup vs baseline: 1.7215x; 1.0132x over previous
//
#include <hip/hip_runtime.h>
#include <stdint.h>

#define GENE_N  200000
#define BATCH   200000
#define EMBED   128
#define BM      32
#define THREADS 512
#define L2E     1.44269504088896340736f

typedef __attribute__((ext_vector_type(8))) short bf16x8;
typedef __attribute__((ext_vector_type(4))) float f32x4;

static __device__ __forceinline__ short f2bf(float f) {
    unsigned u = __builtin_bit_cast(unsigned, f);
    unsigned r = (u + 0x7fffu + ((u >> 16) & 1u)) >> 16;   // RNE
    return (short)(r & 0xffffu);
}
static __device__ __forceinline__ unsigned cvt_pk_bf16(float lo, float hi) {
    unsigned r;
    asm("v_cvt_pk_bf16_f32 %0, %1, %2" : "=v"(r) : "v"(lo), "v"(hi));
    return r;
}
// async global->LDS, 16B per lane: dest = wave-uniform base + lane*16,
// source is PER-LANE (gather!). Increments vmcnt.
static __device__ __forceinline__ void gload16(const float* src, float* lds_dst) {
    __builtin_amdgcn_global_load_lds(
        (const __attribute__((address_space(1))) void*)src,
        (__attribute__((address_space(3))) void*)lds_dst,
        16, 0, 0);
}

// r10: r6 dataflow, but staging = global_load_lds f32 (no register round-trip,
// no lgkm drain, no cvt at stage). cvt_pk at fragment read. XOR swizzle:
// physical 16B-slot s' of row r holds logical chunk s'^(r&7) (involution);
// achieved by pre-swizzling the per-lane GLOBAL source (rule #21) since
// gload_lds writes LDS linearly. Counted vmcnt {2,10,8} keeps stores+ids in
// flight across the single per-tile barrier.
__global__ __launch_bounds__(THREADS, 4)
void hetagg_kernel(const float* __restrict__ gene_feat,
                   const float* __restrict__ cell_feat,
                   const float* __restrict__ gWf, const float* __restrict__ gbf,
                   const float* __restrict__ gWb, const float* __restrict__ gbb,
                   const float* __restrict__ cWf, const float* __restrict__ cbf,
                   const float* __restrict__ cWb, const float* __restrict__ cbb,
                   const int* __restrict__ c_ids, const int* __restrict__ p_ids,
                   const int* __restrict__ n_ids, float* __restrict__ out,
                   int gene_blocks, int cell_blocks)
{
    __shared__ float A_lds[2][BM * EMBED];   // 2 x 16 KB, f32

    const int  bid     = blockIdx.x;
    const bool is_gene = (bid < gene_blocks);
    const int  tid     = threadIdx.x;
    const int  wid     = tid >> 6;
    const int  lane    = tid & 63;
    const int  lgrp    = lane >> 4;   // 0..3
    const int  lcol    = lane & 15;   // 0..15
    const int  dir     = wid >> 2;    // 0 fwd, 1 bwd
    const int  jt      = wid & 3;     // 16-wide j block
    const int  j       = jt * 16 + lcol;

    const float* feat = is_gene ? gene_feat : cell_feat;
    const float* W    = is_gene ? (dir ? gWb : gWf) : (dir ? cWb : cWf);
    const float* Bv   = is_gene ? (dir ? gbb : gbf) : (dir ? cbb : cbf);

    // exp2-domain gate scales folded into weights:
    //   a0 = -i*log2e (u=2^a0=e^-i); a1 = 2g*log2e (v=e^{2g}); a2 = -o*log2e (w=e^-o)
    const float gsc[3] = {-L2E, 2.0f * L2E, -L2E};
    const float b0 = -L2E * Bv[j];
    const float b1 = 2.0f * L2E * Bv[128 + j];
    const float b2 = -L2E * Bv[192 + j];

    // B fragments in registers for the whole kernel (pre-scaled)
    bf16x8 bfrag[3][4];
    {
        const int gate_base[3] = {0, 128, 192};
#pragma unroll
        for (int q = 0; q < 3; ++q) {
            const float* wrow = W + (size_t)(gate_base[q] + j) * EMBED;
            const float  sc   = gsc[q];
#pragma unroll
            for (int s = 0; s < 4; ++s) {
                const int k0 = s * 32 + lgrp * 8;
                float4 w0 = *(const float4*)(wrow + k0);
                float4 w1 = *(const float4*)(wrow + k0 + 4);
                bf16x8 b;
                b[0] = f2bf(sc * w0.x); b[1] = f2bf(sc * w0.y);
                b[2] = f2bf(sc * w0.z); b[3] = f2bf(sc * w0.w);
                b[4] = f2bf(sc * w1.x); b[5] = f2bf(sc * w1.y);
                b[6] = f2bf(sc * w1.z); b[7] = f2bf(sc * w1.w);
                bfrag[q][s] = b;
            }
        }
    }

    const int myb    = is_gene ? bid : (bid - gene_blocks);
    const int nb     = is_gene ? gene_blocks : cell_blocks;
    const int ntiles = is_gene ? (BATCH / BM) : (2 * BATCH / BM);
    const int nk     = (ntiles - myb + nb - 1) / nb;

    // ---- per-lane staging constants (loop-invariant) ----
    const int half   = lane >> 5;          // which row of the staged pair
    const int rb0    = 4 * wid;            // rows rb0+half  (instr p=0)
    const int rb1    = 4 * wid + 2;        // rows rb1+half  (instr p=1)
    const int k0s    = (rb0 + half) & 7;   // row swizzle keys
    const int k1s    = (rb1 + half) & 7;
    const int sc0    = (((lane & 31) ^ k0s) << 2);   // source float offset
    const int sc1    = (((lane & 31) ^ k1s) << 2);
    // ---- per-lane read-side swizzled chunk offsets (floats) ----
    const int rkey = lcol & 7;
    int choff[4][2];
#pragma unroll
    for (int s = 0; s < 4; ++s)
#pragma unroll
        for (int h = 0; h < 2; ++h)
            choff[s][h] = (((s * 8) + lgrp * 2 + h) ^ rkey) << 2;

    // branchless-per-lane id fetch: exactly ONE vmem load per call
    auto fetch_id = [&](int grow) -> int {
        if (is_gene) return c_ids[grow];                    // uniform branch
        const int* arr = (grow < BATCH) ? p_ids : n_ids;    // per-lane select
        const int  off = (grow < BATCH) ? grow : grow - BATCH;
        return arr[off] - GENE_N;
    };

    // ---- prologue: ids(0) -> stage(0) -> ids(1) ----
    int idp0, idp1;
    {
        const int tb = myb * BM;
        idp0 = fetch_id(tb + rb0 + half);
        idp1 = fetch_id(tb + rb1 + half);
        gload16(feat + (size_t)idp0 * EMBED + sc0, &A_lds[0][rb0 * EMBED]);
        gload16(feat + (size_t)idp1 * EMBED + sc1, &A_lds[0][rb1 * EMBED]);
        if (nk > 1) {
            const int tb1 = (myb + nb) * BM;
            idp0 = fetch_id(tb1 + rb0 + half);
            idp1 = fetch_id(tb1 + rb1 + half);
        }
    }

    int pb = 0;
    for (int t = 0; t < nk; ++t, pb ^= 1) {
        // ---- ensure MY stage(t) loads retired, then barrier ----
        // vmcnt N = #vmem ops issued after stage(t) that may be outstanding:
        // t==0: ids(1)=2 (or 0 if nk==1); steady: ids(t+1)=2 + stores(t-1)=8;
        // last tile (no ids issued at t-1): stores only = 8.
        if (t == 0) {
            if (nk > 1) { asm volatile("s_waitcnt vmcnt(2)" ::: "memory"); }
            else        { asm volatile("s_waitcnt vmcnt(0)" ::: "memory"); }
        } else if (t + 1 < nk) {
            asm volatile("s_waitcnt vmcnt(10)" ::: "memory");
        } else {
            asm volatile("s_waitcnt vmcnt(8)" ::: "memory");
        }
        __builtin_amdgcn_s_barrier();
        // barrier => all waves finished reading buf[pb^1] (their reads precede
        // their barrier arrival) => safe to issue stage(t+1) writes into it.

        float* buf = A_lds[pb];

        // ---- issue stage(t+1): pure issue, no register data ----
        if (t + 1 < nk) {
            float* nbuf = A_lds[pb ^ 1];
            gload16(feat + (size_t)idp0 * EMBED + sc0, &nbuf[rb0 * EMBED]);
            gload16(feat + (size_t)idp1 * EMBED + sc1, &nbuf[rb1 * EMBED]);
        }
        // ---- load ids(t+2) (values needed next iteration) ----
        if (t + 2 < nk) {
            const int tb = (myb + (t + 2) * nb) * BM;
            idp0 = fetch_id(tb + rb0 + half);
            idp1 = fetch_id(tb + rb1 + half);
        }

        // ---- compute tile t: swizzled f32 reads -> cvt_pk -> MFMA -> epi ----
        const int base = (myb + t * nb) * BM;
#pragma unroll
        for (int mt = 0; mt < 2; ++mt) {
            f32x4 acc0 = {b0, b0, b0, b0};
            f32x4 acc1 = {b1, b1, b1, b1};
            f32x4 acc2 = {b2, b2, b2, b2};
            const int moff = (mt * 16 + lcol) * EMBED;   // float offset of row
#pragma unroll
            for (int s = 0; s < 4; ++s) {
                f32x4 lo = *(const f32x4*)&buf[moff + choff[s][0]];
                f32x4 hi = *(const f32x4*)&buf[moff + choff[s][1]];
                int4 pk;
                pk.x = (int)cvt_pk_bf16(lo[0], lo[1]);
                pk.y = (int)cvt_pk_bf16(lo[2], lo[3]);
                pk.z = (int)cvt_pk_bf16(hi[0], hi[1]);
                pk.w = (int)cvt_pk_bf16(hi[2], hi[3]);
                bf16x8 a = __builtin_bit_cast(bf16x8, pk);
                acc0 = __builtin_amdgcn_mfma_f32_16x16x32_bf16(a, bfrag[0][s], acc0, 0, 0, 0);
                acc1 = __builtin_amdgcn_mfma_f32_16x16x32_bf16(a, bfrag[1][s], acc1, 0, 0, 0);
                acc2 = __builtin_amdgcn_mfma_f32_16x16x32_bf16(a, bfrag[2][s], acc2, 0, 0, 0);
            }
            // epilogue: h = sigma(o)*tanh(sigma(i)*tanh(g)), exp2 domain
            // u=2^a0, v=2^a1, w=2^a2; c=(v-1)*rcp((1+u)(v+1));
            // tanh(c) ~= c(15+c^2)/(15+6c^2); h = c(15+c^2)*rcp((15+6c^2)(1+w))
#pragma unroll
            for (int r = 0; r < 4; ++r) {
                const float a0 = acc0[r];
                const float a1 = fminf(acc1[r], 80.0f);  // keep v finite
                const float a2 = acc2[r];
                const float u  = __builtin_amdgcn_exp2f(a0);
                const float v  = __builtin_amdgcn_exp2f(a1);
                const float w  = __builtin_amdgcn_exp2f(a2);
                const float tprod = (1.0f + u) * (v + 1.0f);
                const float c  = (v - 1.0f) * __builtin_amdgcn_rcpf(tprod);
                const float c2 = c * c;
                const float num = c * (15.0f + c2);
                const float den = (15.0f + 6.0f * c2) * (1.0f + w);
                const float h   = num * __builtin_amdgcn_rcpf(den);
                const int row   = base + mt * 16 + lgrp * 4 + r;
                const size_t orow = (size_t)(is_gene ? row : (BATCH + row));
                out[orow * 128 + dir * 64 + j] = h;
            }
        }
    }
}

extern "C" void kernel_launch(void* const* d_in, const int* in_sizes, int n_in,
                              void* d_out, int out_size, void* d_ws, size_t ws_size,
                              hipStream_t stream)
{
    const float* gene_feat = (const float*)d_in[0];
    const float* cell_feat = (const float*)d_in[1];
    const float* gWf = (const float*)d_in[2];
    const float* gbf = (const float*)d_in[3];
    const float* gWb = (const float*)d_in[4];
    const float* gbb = (const float*)d_in[5];
    const float* cWf = (const float*)d_in[6];
    const float* cbf = (const float*)d_in[7];
    const float* cWb = (const float*)d_in[8];
    const float* cbb = (const float*)d_in[9];
    const int* c_ids = (const int*)d_in[10];
    const int* p_ids = (const int*)d_in[11];
    const int* n_ids = (const int*)d_in[12];
    float* out = (float*)d_out;

    const int gene_blocks = 341;   // 6250 tiles of 32 rows -> ~18.3/block
    const int cell_blocks = 683;   // 12500 tiles           -> ~18.3/block
    dim3 grid(gene_blocks + cell_blocks);   // 1024 = 2 blocks/CU x 2 rounds
    dim3 block(THREADS);
    hipLaunchKernelGGL(hetagg_kernel, grid, block, 0, stream,
                       gene_feat, cell_feat, gWf, gbf, gWb, gbb,
                       cWf, cbf, cWb, cbb, c_ids, p_ids, n_ids, out,
                       gene_blocks, cell_blocks);
}

// Round 11
// 168.482 us; speedup vs baseline: 1.8424x; 1.0702x over previous
//
#include <hip/hip_runtime.h>

#define GENE_N  200000
#define BATCH   200000
#define EMBED   128
#define BM      32
#define THREADS 512
#define LDS_STRIDE 136   // bf16 elems per LDS row: 128 + 8 pad
#define L2E     1.44269504088896340736f

typedef __attribute__((ext_vector_type(8))) short bf16x8;
typedef __attribute__((ext_vector_type(4))) float f32x4;

static __device__ __forceinline__ short f2bf(float f) {
    unsigned u = __builtin_bit_cast(unsigned, f);
    unsigned r = (u + 0x7fffu + ((u >> 16) & 1u)) >> 16;   // RNE
    return (short)(r & 0xffffu);
}
static __device__ __forceinline__ unsigned cvt_pk_bf16(float lo, float hi) {
    unsigned r;
    asm("v_cvt_pk_bf16_f32 %0, %1, %2" : "=v"(r) : "v"(lo), "v"(hi));
    return r;
}

// r11 = r6 skeleton (best, 154us) + three issue-count reductions:
//  (1) operand-swapped MFMA: D = W_slice . X^T, lane's 4 acc values are 4
//      CONSECUTIVE j for one batch row -> 2x global_store_dwordx4 per tile
//      (was 8 scalar stores). A/B fragment layouts are symmetric for
//      16x16x32 so the swap is register-free; bias becomes per-r vectors.
//  (2) single-rcp epilogue: tanh(N/D)*sigma(o) fused rationally ->
//      3 exp2 + 1 rcp per output (was 3+2). Clamp a<=15 prevents overflow.
//  (3) next-tile gathers issued BEFORE the lgkm-drain+barrier.
__global__ __launch_bounds__(THREADS, 4)
void hetagg_kernel(const float* __restrict__ gene_feat,
                   const float* __restrict__ cell_feat,
                   const float* __restrict__ gWf, const float* __restrict__ gbf,
                   const float* __restrict__ gWb, const float* __restrict__ gbb,
                   const float* __restrict__ cWf, const float* __restrict__ cbf,
                   const float* __restrict__ cWb, const float* __restrict__ cbb,
                   const int* __restrict__ c_ids, const int* __restrict__ p_ids,
                   const int* __restrict__ n_ids, float* __restrict__ out,
                   int gene_blocks, int cell_blocks)
{
    __shared__ short A_lds[2][BM * LDS_STRIDE];

    const int  bid     = blockIdx.x;
    const bool is_gene = (bid < gene_blocks);
    const int  tid     = threadIdx.x;
    const int  wid     = tid >> 6;
    const int  lane    = tid & 63;
    const int  lgrp    = lane >> 4;   // 0..3
    const int  lcol    = lane & 15;   // 0..15
    const int  dir     = wid >> 2;    // 0 fwd, 1 bwd
    const int  jt      = wid & 3;     // 16-wide j block
    const int  j       = jt * 16 + lcol;   // W-row index for fragments

    const float* feat = is_gene ? gene_feat : cell_feat;
    const float* W    = is_gene ? (dir ? gWb : gWf) : (dir ? cWb : cWf);
    const float* Bv   = is_gene ? (dir ? gbb : gbf) : (dir ? cbb : cbf);

    // exp2-domain gate scales folded into weights:
    //   a0 = -i*log2e (u=2^a0=e^-i); a1 = 2g*log2e (v=e^{2g}); a2 = -o*log2e (w=e^-o)
    const float gsc[3] = {-L2E, 2.0f * L2E, -L2E};

    // per-r biases: after the operand swap, acc reg r maps to
    // j_out = jt*16 + lgrp*4 + r (uniform in lcol).
    f32x4 binit0, binit1, binit2;
#pragma unroll
    for (int r = 0; r < 4; ++r) {
        const int jr = jt * 16 + lgrp * 4 + r;
        binit0[r] = -L2E * Bv[jr];
        binit1[r] = 2.0f * L2E * Bv[128 + jr];
        binit2[r] = -L2E * Bv[192 + jr];
    }

    // W fragments (A-operand after swap): lane holds W[jt*16+(lane&15)][k],
    // k = (lane>>4)*8 + s*32 + e  — identical content to the old B-fragment.
    bf16x8 bfrag[3][4];
    {
        const int gate_base[3] = {0, 128, 192};
#pragma unroll
        for (int q = 0; q < 3; ++q) {
            const float* wrow = W + (size_t)(gate_base[q] + j) * EMBED;
            const float  sc   = gsc[q];
#pragma unroll
            for (int s = 0; s < 4; ++s) {
                const int k0 = s * 32 + lgrp * 8;
                float4 w0 = *(const float4*)(wrow + k0);
                float4 w1 = *(const float4*)(wrow + k0 + 4);
                bf16x8 b;
                b[0] = f2bf(sc * w0.x); b[1] = f2bf(sc * w0.y);
                b[2] = f2bf(sc * w0.z); b[3] = f2bf(sc * w0.w);
                b[4] = f2bf(sc * w1.x); b[5] = f2bf(sc * w1.y);
                b[6] = f2bf(sc * w1.z); b[7] = f2bf(sc * w1.w);
                bfrag[q][s] = b;
            }
        }
    }

    const int myb    = is_gene ? bid : (bid - gene_blocks);
    const int nb     = is_gene ? gene_blocks : cell_blocks;
    const int ntiles = is_gene ? (BATCH / BM) : (2 * BATCH / BM);
    const int nk     = (ntiles - myb + nb - 1) / nb;   // tiles for this block

    const int r0 = tid >> 5;   // 0..15 (row within half-pass)
    const int cc = tid & 31;   // float4 col within row

#define FETCH_ID(grow) (is_gene ? c_ids[(grow)] \
                       : ((grow) < BATCH ? p_ids[(grow)] - GENE_N \
                                         : n_ids[(grow) - BATCH] - GENE_N))

    // ---- depth-2 pipeline prologue: rows(0)->rvA, rows(1)->rvB, ids(2)->idC
    float4 rvA[2], rvB[2];
    int    idC[2];
    {
        int id0[2], id1[2];
        const int ta = myb * BM;
#pragma unroll
        for (int p = 0; p < 2; ++p) id0[p] = FETCH_ID(ta + r0 + p * 16);
#pragma unroll
        for (int p = 0; p < 2; ++p)
            rvA[p] = ((const float4*)(feat + (size_t)id0[p] * EMBED))[cc];
        if (nk > 1) {
            const int tb = (myb + nb) * BM;
#pragma unroll
            for (int p = 0; p < 2; ++p) id1[p] = FETCH_ID(tb + r0 + p * 16);
#pragma unroll
            for (int p = 0; p < 2; ++p)
                rvB[p] = ((const float4*)(feat + (size_t)id1[p] * EMBED))[cc];
        }
        if (nk > 2) {
            const int tc = (myb + 2 * nb) * BM;
#pragma unroll
            for (int p = 0; p < 2; ++p) idC[p] = FETCH_ID(tc + r0 + p * 16);
        }
    }

    int pb = 0;   // LDS buffer parity

    // Tile body: stage RV -> issue prefetch (k+2 rows, k+3 ids) -> drain ->
    // barrier -> MFMA(swapped) + fused single-rcp epilogue + float4 store.
#define TILE_BODY(K, RV)                                                        \
    {                                                                           \
        const int t_    = myb + (K) * nb;                                       \
        const int base_ = t_ * BM;                                              \
        short* buf = A_lds[pb];                                                 \
        _Pragma("unroll")                                                       \
        for (int p = 0; p < 2; ++p) {                                           \
            int2 sv;                                                            \
            sv.x = (int)cvt_pk_bf16(RV[p].x, RV[p].y);                          \
            sv.y = (int)cvt_pk_bf16(RV[p].z, RV[p].w);                          \
            *(int2*)&buf[(r0 + p * 16) * LDS_STRIDE + cc * 4] = sv;             \
        }                                                                       \
        /* issue next gathers BEFORE the drain: fly during barrier+compute */   \
        if ((K) + 2 < nk) {                                                     \
            _Pragma("unroll")                                                   \
            for (int p = 0; p < 2; ++p)                                         \
                RV[p] = ((const float4*)(feat + (size_t)idC[p] * EMBED))[cc];   \
        }                                                                       \
        if ((K) + 3 < nk) {                                                     \
            const int tn_ = (myb + ((K) + 3) * nb) * BM;                        \
            _Pragma("unroll")                                                   \
            for (int p = 0; p < 2; ++p) idC[p] = FETCH_ID(tn_ + r0 + p * 16);   \
        }                                                                       \
        asm volatile("s_waitcnt lgkmcnt(0)" ::: "memory");                      \
        __builtin_amdgcn_s_barrier();                                           \
        _Pragma("unroll")                                                       \
        for (int mt = 0; mt < 2; ++mt) {                                        \
            f32x4 acc0 = binit0;                                                \
            f32x4 acc1 = binit1;                                                \
            f32x4 acc2 = binit2;                                                \
            const int m_ = mt * 16 + lcol;                                      \
            _Pragma("unroll")                                                   \
            for (int s = 0; s < 4; ++s) {                                       \
                bf16x8 a = *(const bf16x8*)&buf[m_ * LDS_STRIDE + s * 32 + lgrp * 8]; \
                acc0 = __builtin_amdgcn_mfma_f32_16x16x32_bf16(bfrag[0][s], a, acc0, 0, 0, 0); \
                acc1 = __builtin_amdgcn_mfma_f32_16x16x32_bf16(bfrag[1][s], a, acc1, 0, 0, 0); \
                acc2 = __builtin_amdgcn_mfma_f32_16x16x32_bf16(bfrag[2][s], a, acc2, 0, 0, 0); \
            }                                                                   \
            /* h = sigma(o)*tanh(sigma(i)*tanh(g)); c=N/D, Pade folded: */      \
            /* h = N(15D^2+N^2) * rcp(D(15D^2+6N^2)(1+w)); clamp a<=15  */      \
            float4 hv;                                                          \
            _Pragma("unroll")                                                   \
            for (int r = 0; r < 4; ++r) {                                       \
                const float a0 = fminf(acc0[r], 15.0f);                         \
                const float a1 = fminf(acc1[r], 15.0f);                         \
                const float a2 = fminf(acc2[r], 15.0f);                         \
                const float u  = __builtin_amdgcn_exp2f(a0);                    \
                const float v  = __builtin_amdgcn_exp2f(a1);                    \
                const float w  = __builtin_amdgcn_exp2f(a2);                    \
                const float N  = v - 1.0f;                                      \
                const float D  = (1.0f + u) * (v + 1.0f);                       \
                const float D2 = D * D;                                         \
                const float N2 = N * N;                                         \
                const float t1 = fmaf(15.0f, D2, N2);                           \
                const float t2 = fmaf(5.0f, N2, t1);                            \
                const float num = N * t1;                                       \
                const float den = D * t2 * (1.0f + w);                          \
                hv[r] = num * __builtin_amdgcn_rcpf(den);                       \
            }                                                                   \
            const int row = base_ + mt * 16 + lcol;                             \
            const size_t orow = (size_t)(is_gene ? row : (BATCH + row));        \
            *(float4*)&out[orow * 128 + dir * 64 + jt * 16 + lgrp * 4] =        \
                *(const float4*)&hv;                                            \
        }                                                                       \
        pb ^= 1;                                                                \
    }

    int k = 0;
    for (; k + 1 < nk; k += 2) {
        TILE_BODY(k, rvA);
        TILE_BODY(k + 1, rvB);
    }
    if (k < nk) TILE_BODY(k, rvA);

#undef TILE_BODY
#undef FETCH_ID
}

extern "C" void kernel_launch(void* const* d_in, const int* in_sizes, int n_in,
                              void* d_out, int out_size, void* d_ws, size_t ws_size,
                              hipStream_t stream)
{
    const float* gene_feat = (const float*)d_in[0];
    const float* cell_feat = (const float*)d_in[1];
    const float* gWf = (const float*)d_in[2];
    const float* gbf = (const float*)d_in[3];
    const float* gWb = (const float*)d_in[4];
    const float* gbb = (const float*)d_in[5];
    const float* cWf = (const float*)d_in[6];
    const float* cbf = (const float*)d_in[7];
    const float* cWb = (const float*)d_in[8];
    const float* cbb = (const float*)d_in[9];
    const int* c_ids = (const int*)d_in[10];
    const int* p_ids = (const int*)d_in[11];
    const int* n_ids = (const int*)d_in[12];
    float* out = (float*)d_out;

    const int gene_blocks = 171;   // 6250 tiles of 32 rows -> 36-37 tiles/block
    const int cell_blocks = 341;   // 12500 tiles           -> 36-37 tiles/block
    dim3 grid(gene_blocks + cell_blocks);   // 512 = 2 blocks/CU, one round
    dim3 block(THREADS);
    hipLaunchKernelGGL(hetagg_kernel, grid, block, 0, stream,
                       gene_feat, cell_feat, gWf, gbf, gWb, gbb,
                       cWf, cbf, cWb, cbb, c_ids, p_ids, n_ids, out,
                       gene_blocks, cell_blocks);
}

// Round 13
// 138.582 us; speedup vs baseline: 2.2399x; 1.2158x over previous
//
#include <hip/hip_runtime.h>

#define GENE_N  200000
#define BATCH   200000
#define EMBED   128
#define BM      32
#define THREADS 512
#define LDS_STRIDE 136   // bf16 elems per LDS row: 128 + 8 pad
#define L2E     1.44269504088896340736f

typedef __attribute__((ext_vector_type(8))) short bf16x8;
typedef __attribute__((ext_vector_type(4))) float f32x4;

static __device__ __forceinline__ short f2bf(float f) {
    unsigned u = __builtin_bit_cast(unsigned, f);
    unsigned r = (u + 0x7fffu + ((u >> 16) & 1u)) >> 16;   // RNE
    return (short)(r & 0xffffu);
}
static __device__ __forceinline__ unsigned cvt_pk_bf16(float lo, float hi) {
    unsigned r;
    asm("v_cvt_pk_bf16_f32 %0, %1, %2" : "=v"(r) : "v"(lo), "v"(hi));
    return r;
}

// r13 = r12 with the nontemporal-store type fixed (ext_vector f32x4, not
// HIP_vector_type float4 — the builtin rejects struct types).
// Mechanism under test: output stores (307 MB/pass) evict the 153 MB feature
// tables from the 256 MB L3 every pass -> all gathers are HBM-latency.
// nt stores keep the tables L3-resident; gathers become L3 hits and the
// depth-2 prefetch over-covers the latency.
__global__ __launch_bounds__(THREADS, 4)
void hetagg_kernel(const float* __restrict__ gene_feat,
                   const float* __restrict__ cell_feat,
                   const float* __restrict__ gWf, const float* __restrict__ gbf,
                   const float* __restrict__ gWb, const float* __restrict__ gbb,
                   const float* __restrict__ cWf, const float* __restrict__ cbf,
                   const float* __restrict__ cWb, const float* __restrict__ cbb,
                   const int* __restrict__ c_ids, const int* __restrict__ p_ids,
                   const int* __restrict__ n_ids, float* __restrict__ out,
                   int gene_blocks, int cell_blocks)
{
    __shared__ short A_lds[2][BM * LDS_STRIDE];

    const int  bid     = blockIdx.x;
    const bool is_gene = (bid < gene_blocks);
    const int  tid     = threadIdx.x;
    const int  wid     = tid >> 6;
    const int  lane    = tid & 63;
    const int  lgrp    = lane >> 4;   // 0..3
    const int  lcol    = lane & 15;   // 0..15
    const int  dir     = wid >> 2;    // 0 fwd, 1 bwd
    const int  jt      = wid & 3;     // 16-wide j block
    const int  j       = jt * 16 + lcol;   // W-row index for fragments

    const float* feat = is_gene ? gene_feat : cell_feat;
    const float* W    = is_gene ? (dir ? gWb : gWf) : (dir ? cWb : cWf);
    const float* Bv   = is_gene ? (dir ? gbb : gbf) : (dir ? cbb : cbf);

    // exp2-domain gate scales folded into weights:
    //   a0 = -i*log2e (u=2^a0=e^-i); a1 = 2g*log2e (v=e^{2g}); a2 = -o*log2e (w=e^-o)
    const float gsc[3] = {-L2E, 2.0f * L2E, -L2E};

    // per-r biases: after the operand swap, acc reg r maps to
    // j_out = jt*16 + lgrp*4 + r (uniform in lcol).
    f32x4 binit0, binit1, binit2;
#pragma unroll
    for (int r = 0; r < 4; ++r) {
        const int jr = jt * 16 + lgrp * 4 + r;
        binit0[r] = -L2E * Bv[jr];
        binit1[r] = 2.0f * L2E * Bv[128 + jr];
        binit2[r] = -L2E * Bv[192 + jr];
    }

    // W fragments (A-operand after swap): lane holds W[jt*16+(lane&15)][k],
    // k = (lane>>4)*8 + s*32 + e
    bf16x8 bfrag[3][4];
    {
        const int gate_base[3] = {0, 128, 192};
#pragma unroll
        for (int q = 0; q < 3; ++q) {
            const float* wrow = W + (size_t)(gate_base[q] + j) * EMBED;
            const float  sc   = gsc[q];
#pragma unroll
            for (int s = 0; s < 4; ++s) {
                const int k0 = s * 32 + lgrp * 8;
                float4 w0 = *(const float4*)(wrow + k0);
                float4 w1 = *(const float4*)(wrow + k0 + 4);
                bf16x8 b;
                b[0] = f2bf(sc * w0.x); b[1] = f2bf(sc * w0.y);
                b[2] = f2bf(sc * w0.z); b[3] = f2bf(sc * w0.w);
                b[4] = f2bf(sc * w1.x); b[5] = f2bf(sc * w1.y);
                b[6] = f2bf(sc * w1.z); b[7] = f2bf(sc * w1.w);
                bfrag[q][s] = b;
            }
        }
    }

    const int myb    = is_gene ? bid : (bid - gene_blocks);
    const int nb     = is_gene ? gene_blocks : cell_blocks;
    const int ntiles = is_gene ? (BATCH / BM) : (2 * BATCH / BM);
    const int nk     = (ntiles - myb + nb - 1) / nb;   // tiles for this block

    const int r0 = tid >> 5;   // 0..15 (row within half-pass)
    const int cc = tid & 31;   // float4 col within row

#define FETCH_ID(grow) (is_gene ? c_ids[(grow)] \
                       : ((grow) < BATCH ? p_ids[(grow)] - GENE_N \
                                         : n_ids[(grow) - BATCH] - GENE_N))

    // ---- depth-2 pipeline prologue: rows(0)->rvA, rows(1)->rvB, ids(2)->idC
    float4 rvA[2], rvB[2];
    int    idC[2];
    {
        int id0[2], id1[2];
        const int ta = myb * BM;
#pragma unroll
        for (int p = 0; p < 2; ++p) id0[p] = FETCH_ID(ta + r0 + p * 16);
#pragma unroll
        for (int p = 0; p < 2; ++p)
            rvA[p] = ((const float4*)(feat + (size_t)id0[p] * EMBED))[cc];
        if (nk > 1) {
            const int tb = (myb + nb) * BM;
#pragma unroll
            for (int p = 0; p < 2; ++p) id1[p] = FETCH_ID(tb + r0 + p * 16);
#pragma unroll
            for (int p = 0; p < 2; ++p)
                rvB[p] = ((const float4*)(feat + (size_t)id1[p] * EMBED))[cc];
        }
        if (nk > 2) {
            const int tc = (myb + 2 * nb) * BM;
#pragma unroll
            for (int p = 0; p < 2; ++p) idC[p] = FETCH_ID(tc + r0 + p * 16);
        }
    }

    int pb = 0;   // LDS buffer parity

    // Tile body (r6 order): stage RV -> drain+barrier -> issue prefetch
    // (k+2 rows, k+3 ids) -> MFMA(swapped) + single-rcp epilogue + nt store.
#define TILE_BODY(K, RV)                                                        \
    {                                                                           \
        const int t_    = myb + (K) * nb;                                       \
        const int base_ = t_ * BM;                                              \
        short* buf = A_lds[pb];                                                 \
        _Pragma("unroll")                                                       \
        for (int p = 0; p < 2; ++p) {                                           \
            int2 sv;                                                            \
            sv.x = (int)cvt_pk_bf16(RV[p].x, RV[p].y);                          \
            sv.y = (int)cvt_pk_bf16(RV[p].z, RV[p].w);                          \
            *(int2*)&buf[(r0 + p * 16) * LDS_STRIDE + cc * 4] = sv;             \
        }                                                                       \
        asm volatile("s_waitcnt lgkmcnt(0)" ::: "memory");                      \
        __builtin_amdgcn_s_barrier();                                           \
        if ((K) + 2 < nk) {                                                     \
            _Pragma("unroll")                                                   \
            for (int p = 0; p < 2; ++p)                                         \
                RV[p] = ((const float4*)(feat + (size_t)idC[p] * EMBED))[cc];   \
        }                                                                       \
        if ((K) + 3 < nk) {                                                     \
            const int tn_ = (myb + ((K) + 3) * nb) * BM;                        \
            _Pragma("unroll")                                                   \
            for (int p = 0; p < 2; ++p) idC[p] = FETCH_ID(tn_ + r0 + p * 16);   \
        }                                                                       \
        _Pragma("unroll")                                                       \
        for (int mt = 0; mt < 2; ++mt) {                                        \
            f32x4 acc0 = binit0;                                                \
            f32x4 acc1 = binit1;                                                \
            f32x4 acc2 = binit2;                                                \
            const int m_ = mt * 16 + lcol;                                      \
            _Pragma("unroll")                                                   \
            for (int s = 0; s < 4; ++s) {                                       \
                bf16x8 a = *(const bf16x8*)&buf[m_ * LDS_STRIDE + s * 32 + lgrp * 8]; \
                acc0 = __builtin_amdgcn_mfma_f32_16x16x32_bf16(bfrag[0][s], a, acc0, 0, 0, 0); \
                acc1 = __builtin_amdgcn_mfma_f32_16x16x32_bf16(bfrag[1][s], a, acc1, 0, 0, 0); \
                acc2 = __builtin_amdgcn_mfma_f32_16x16x32_bf16(bfrag[2][s], a, acc2, 0, 0, 0); \
            }                                                                   \
            /* h = sigma(o)*tanh(sigma(i)*tanh(g)); c=N/D, Pade folded: */      \
            /* h = N(15D^2+N^2) * rcp(D(15D^2+6N^2)(1+w)); clamp a<=15  */      \
            f32x4 hv;                                                           \
            _Pragma("unroll")                                                   \
            for (int r = 0; r < 4; ++r) {                                       \
                const float a0 = fminf(acc0[r], 15.0f);                         \
                const float a1 = fminf(acc1[r], 15.0f);                         \
                const float a2 = fminf(acc2[r], 15.0f);                         \
                const float u  = __builtin_amdgcn_exp2f(a0);                    \
                const float v  = __builtin_amdgcn_exp2f(a1);                    \
                const float w  = __builtin_amdgcn_exp2f(a2);                    \
                const float N  = v - 1.0f;                                      \
                const float D  = (1.0f + u) * (v + 1.0f);                       \
                const float D2 = D * D;                                         \
                const float N2 = N * N;                                         \
                const float t1 = fmaf(15.0f, D2, N2);                           \
                const float t2 = fmaf(5.0f, N2, t1);                            \
                const float num = N * t1;                                       \
                const float den = D * t2 * (1.0f + w);                          \
                hv[r] = num * __builtin_amdgcn_rcpf(den);                       \
            }                                                                   \
            const int row = base_ + mt * 16 + lcol;                             \
            const size_t orow = (size_t)(is_gene ? row : (BATCH + row));        \
            __builtin_nontemporal_store(hv,                                     \
                (f32x4*)&out[orow * 128 + dir * 64 + jt * 16 + lgrp * 4]);      \
        }                                                                       \
        pb ^= 1;                                                                \
    }

    int k = 0;
    for (; k + 1 < nk; k += 2) {
        TILE_BODY(k, rvA);
        TILE_BODY(k + 1, rvB);
    }
    if (k < nk) TILE_BODY(k, rvA);

#undef TILE_BODY
#undef FETCH_ID
}

extern "C" void kernel_launch(void* const* d_in, const int* in_sizes, int n_in,
                              void* d_out, int out_size, void* d_ws, size_t ws_size,
                              hipStream_t stream)
{
    const float* gene_feat = (const float*)d_in[0];
    const float* cell_feat = (const float*)d_in[1];
    const float* gWf = (const float*)d_in[2];
    const float* gbf = (const float*)d_in[3];
    const float* gWb = (const float*)d_in[4];
    const float* gbb = (const float*)d_in[5];
    const float* cWf = (const float*)d_in[6];
    const float* cbf = (const float*)d_in[7];
    const float* cWb = (const float*)d_in[8];
    const float* cbb = (const float*)d_in[9];
    const int* c_ids = (const int*)d_in[10];
    const int* p_ids = (const int*)d_in[11];
    const int* n_ids = (const int*)d_in[12];
    float* out = (float*)d_out;

    const int gene_blocks = 171;   // 6250 tiles of 32 rows -> 36-37 tiles/block
    const int cell_blocks = 341;   // 12500 tiles           -> 36-37 tiles/block
    dim3 grid(gene_blocks + cell_blocks);   // 512 = 2 blocks/CU, one round
    dim3 block(THREADS);
    hipLaunchKernelGGL(hetagg_kernel, grid, block, 0, stream,
                       gene_feat, cell_feat, gWf, gbf, gWb, gbb,
                       cWf, cbf, cWb, cbb, c_ids, p_ids, n_ids, out,
                       gene_blocks, cell_blocks);
}

// Round 14
// 137.346 us; speedup vs baseline: 2.2600x; 1.0090x over previous
//
#include <hip/hip_runtime.h>

#define GENE_N  200000
#define BATCH   200000
#define EMBED   128
#define BM      32
#define THREADS 512
#define LDS_STRIDE 136   // bf16 elems per LDS row: 128 + 8 pad
#define L2E     1.44269504088896340736f

typedef __attribute__((ext_vector_type(8))) short bf16x8;
typedef __attribute__((ext_vector_type(4))) float f32x4;

static __device__ __forceinline__ short f2bf(float f) {
    unsigned u = __builtin_bit_cast(unsigned, f);
    unsigned r = (u + 0x7fffu + ((u >> 16) & 1u)) >> 16;   // RNE
    return (short)(r & 0xffffu);
}
static __device__ __forceinline__ unsigned cvt_pk_bf16(float lo, float hi) {
    unsigned r;
    asm("v_cvt_pk_bf16_f32 %0, %1, %2" : "=v"(r) : "v"(lo), "v"(hi));
    return r;
}

// r14 = r13 with ONE change: id fetches moved to the TOP of each tile body,
// double-banked (idE/idO).
// Why: s_waitcnt vmcnt waits on the YOUNGEST outstanding load by draining to
// a count — r13 issued [rows(K+1)] then [idC]; using idC at body K forced
// vmcnt(0), draining rows(K+1) mid-body, every body -> depth-2 prefetch was
// effectively depth-1. New order puts ids(K+3) BEFORE rows(K+2) in the FIFO,
// so consuming ids at body K+1 leaves rows(K+2) (and the next id fetch)
// in flight. True 2-body (~1000-1400 cyc) cover of gather latency.
__global__ __launch_bounds__(THREADS, 4)
void hetagg_kernel(const float* __restrict__ gene_feat,
                   const float* __restrict__ cell_feat,
                   const float* __restrict__ gWf, const float* __restrict__ gbf,
                   const float* __restrict__ gWb, const float* __restrict__ gbb,
                   const float* __restrict__ cWf, const float* __restrict__ cbf,
                   const float* __restrict__ cWb, const float* __restrict__ cbb,
                   const int* __restrict__ c_ids, const int* __restrict__ p_ids,
                   const int* __restrict__ n_ids, float* __restrict__ out,
                   int gene_blocks, int cell_blocks)
{
    __shared__ short A_lds[2][BM * LDS_STRIDE];

    const int  bid     = blockIdx.x;
    const bool is_gene = (bid < gene_blocks);
    const int  tid     = threadIdx.x;
    const int  wid     = tid >> 6;
    const int  lane    = tid & 63;
    const int  lgrp    = lane >> 4;   // 0..3
    const int  lcol    = lane & 15;   // 0..15
    const int  dir     = wid >> 2;    // 0 fwd, 1 bwd
    const int  jt      = wid & 3;     // 16-wide j block
    const int  j       = jt * 16 + lcol;   // W-row index for fragments

    const float* feat = is_gene ? gene_feat : cell_feat;
    const float* W    = is_gene ? (dir ? gWb : gWf) : (dir ? cWb : cWf);
    const float* Bv   = is_gene ? (dir ? gbb : gbf) : (dir ? cbb : cbf);

    // exp2-domain gate scales folded into weights:
    //   a0 = -i*log2e (u=2^a0=e^-i); a1 = 2g*log2e (v=e^{2g}); a2 = -o*log2e (w=e^-o)
    const float gsc[3] = {-L2E, 2.0f * L2E, -L2E};

    // per-r biases: after the operand swap, acc reg r maps to
    // j_out = jt*16 + lgrp*4 + r (uniform in lcol).
    f32x4 binit0, binit1, binit2;
#pragma unroll
    for (int r = 0; r < 4; ++r) {
        const int jr = jt * 16 + lgrp * 4 + r;
        binit0[r] = -L2E * Bv[jr];
        binit1[r] = 2.0f * L2E * Bv[128 + jr];
        binit2[r] = -L2E * Bv[192 + jr];
    }

    // W fragments (A-operand after swap): lane holds W[jt*16+(lane&15)][k],
    // k = (lane>>4)*8 + s*32 + e
    bf16x8 bfrag[3][4];
    {
        const int gate_base[3] = {0, 128, 192};
#pragma unroll
        for (int q = 0; q < 3; ++q) {
            const float* wrow = W + (size_t)(gate_base[q] + j) * EMBED;
            const float  sc   = gsc[q];
#pragma unroll
            for (int s = 0; s < 4; ++s) {
                const int k0 = s * 32 + lgrp * 8;
                float4 w0 = *(const float4*)(wrow + k0);
                float4 w1 = *(const float4*)(wrow + k0 + 4);
                bf16x8 b;
                b[0] = f2bf(sc * w0.x); b[1] = f2bf(sc * w0.y);
                b[2] = f2bf(sc * w0.z); b[3] = f2bf(sc * w0.w);
                b[4] = f2bf(sc * w1.x); b[5] = f2bf(sc * w1.y);
                b[6] = f2bf(sc * w1.z); b[7] = f2bf(sc * w1.w);
                bfrag[q][s] = b;
            }
        }
    }

    const int myb    = is_gene ? bid : (bid - gene_blocks);
    const int nb     = is_gene ? gene_blocks : cell_blocks;
    const int ntiles = is_gene ? (BATCH / BM) : (2 * BATCH / BM);
    const int nk     = (ntiles - myb + nb - 1) / nb;   // tiles for this block

    const int r0 = tid >> 5;   // 0..15 (row within half-pass)
    const int cc = tid & 31;   // float4 col within row

#define FETCH_ID(grow) (is_gene ? c_ids[(grow)] \
                       : ((grow) < BATCH ? p_ids[(grow)] - GENE_N \
                                         : n_ids[(grow) - BATCH] - GENE_N))

    // ---- prologue: rows(0)->rvA, rows(1)->rvB, ids(2)->idO ----
    float4 rvA[2], rvB[2];
    int    idE[2], idO[2];
    {
        int id0[2], id1[2];
        const int ta = myb * BM;
#pragma unroll
        for (int p = 0; p < 2; ++p) id0[p] = FETCH_ID(ta + r0 + p * 16);
#pragma unroll
        for (int p = 0; p < 2; ++p)
            rvA[p] = ((const float4*)(feat + (size_t)id0[p] * EMBED))[cc];
        if (nk > 1) {
            const int tb = (myb + nb) * BM;
#pragma unroll
            for (int p = 0; p < 2; ++p) id1[p] = FETCH_ID(tb + r0 + p * 16);
#pragma unroll
            for (int p = 0; p < 2; ++p)
                rvB[p] = ((const float4*)(feat + (size_t)id1[p] * EMBED))[cc];
        }
        if (nk > 2) {
            const int tc = (myb + 2 * nb) * BM;
#pragma unroll
            for (int p = 0; p < 2; ++p) idO[p] = FETCH_ID(tc + r0 + p * 16);
        }
    }

    int pb = 0;   // LDS buffer parity

    // Tile body: [fetch ids(K+3) -> IDF, FIRST in FIFO] -> stage RV ->
    // drain+barrier -> refill RV=rows(K+2) via IDU (fetched last body, ahead
    // of rows(K+1) in FIFO -> no spurious drain) -> MFMA + epilogue + nt store.
#define TILE_BODY(K, RV, IDF, IDU)                                             \
    {                                                                           \
        const int t_    = myb + (K) * nb;                                       \
        const int base_ = t_ * BM;                                              \
        short* buf = A_lds[pb];                                                 \
        if ((K) + 3 < nk) {                                                     \
            const int tn_ = (myb + ((K) + 3) * nb) * BM;                        \
            _Pragma("unroll")                                                   \
            for (int p = 0; p < 2; ++p) IDF[p] = FETCH_ID(tn_ + r0 + p * 16);   \
        }                                                                       \
        _Pragma("unroll")                                                       \
        for (int p = 0; p < 2; ++p) {                                           \
            int2 sv;                                                            \
            sv.x = (int)cvt_pk_bf16(RV[p].x, RV[p].y);                          \
            sv.y = (int)cvt_pk_bf16(RV[p].z, RV[p].w);                          \
            *(int2*)&buf[(r0 + p * 16) * LDS_STRIDE + cc * 4] = sv;             \
        }                                                                       \
        asm volatile("s_waitcnt lgkmcnt(0)" ::: "memory");                      \
        __builtin_amdgcn_s_barrier();                                           \
        if ((K) + 2 < nk) {                                                     \
            _Pragma("unroll")                                                   \
            for (int p = 0; p < 2; ++p)                                         \
                RV[p] = ((const float4*)(feat + (size_t)IDU[p] * EMBED))[cc];   \
        }                                                                       \
        _Pragma("unroll")                                                       \
        for (int mt = 0; mt < 2; ++mt) {                                        \
            f32x4 acc0 = binit0;                                                \
            f32x4 acc1 = binit1;                                                \
            f32x4 acc2 = binit2;                                                \
            const int m_ = mt * 16 + lcol;                                      \
            _Pragma("unroll")                                                   \
            for (int s = 0; s < 4; ++s) {                                       \
                bf16x8 a = *(const bf16x8*)&buf[m_ * LDS_STRIDE + s * 32 + lgrp * 8]; \
                acc0 = __builtin_amdgcn_mfma_f32_16x16x32_bf16(bfrag[0][s], a, acc0, 0, 0, 0); \
                acc1 = __builtin_amdgcn_mfma_f32_16x16x32_bf16(bfrag[1][s], a, acc1, 0, 0, 0); \
                acc2 = __builtin_amdgcn_mfma_f32_16x16x32_bf16(bfrag[2][s], a, acc2, 0, 0, 0); \
            }                                                                   \
            /* h = sigma(o)*tanh(sigma(i)*tanh(g)); c=N/D, Pade folded: */      \
            /* h = N(15D^2+N^2) * rcp(D(15D^2+6N^2)(1+w)); clamp a<=15  */      \
            f32x4 hv;                                                           \
            _Pragma("unroll")                                                   \
            for (int r = 0; r < 4; ++r) {                                       \
                const float a0 = fminf(acc0[r], 15.0f);                         \
                const float a1 = fminf(acc1[r], 15.0f);                         \
                const float a2 = fminf(acc2[r], 15.0f);                         \
                const float u  = __builtin_amdgcn_exp2f(a0);                    \
                const float v  = __builtin_amdgcn_exp2f(a1);                    \
                const float w  = __builtin_amdgcn_exp2f(a2);                    \
                const float N  = v - 1.0f;                                      \
                const float D  = (1.0f + u) * (v + 1.0f);                       \
                const float D2 = D * D;                                         \
                const float N2 = N * N;                                         \
                const float t1 = fmaf(15.0f, D2, N2);                           \
                const float t2 = fmaf(5.0f, N2, t1);                            \
                const float num = N * t1;                                       \
                const float den = D * t2 * (1.0f + w);                          \
                hv[r] = num * __builtin_amdgcn_rcpf(den);                       \
            }                                                                   \
            const int row = base_ + mt * 16 + lcol;                             \
            const size_t orow = (size_t)(is_gene ? row : (BATCH + row));        \
            __builtin_nontemporal_store(hv,                                     \
                (f32x4*)&out[orow * 128 + dir * 64 + jt * 16 + lgrp * 4]);      \
        }                                                                       \
        pb ^= 1;                                                                \
    }

    int k = 0;
    for (; k + 1 < nk; k += 2) {
        TILE_BODY(k, rvA, idE, idO);       // fetch ids(k+3)->idE, use idO
        TILE_BODY(k + 1, rvB, idO, idE);   // fetch ids(k+4)->idO, use idE
    }
    if (k < nk) TILE_BODY(k, rvA, idE, idO);

#undef TILE_BODY
#undef FETCH_ID
}

extern "C" void kernel_launch(void* const* d_in, const int* in_sizes, int n_in,
                              void* d_out, int out_size, void* d_ws, size_t ws_size,
                              hipStream_t stream)
{
    const float* gene_feat = (const float*)d_in[0];
    const float* cell_feat = (const float*)d_in[1];
    const float* gWf = (const float*)d_in[2];
    const float* gbf = (const float*)d_in[3];
    const float* gWb = (const float*)d_in[4];
    const float* gbb = (const float*)d_in[5];
    const float* cWf = (const float*)d_in[6];
    const float* cbf = (const float*)d_in[7];
    const float* cWb = (const float*)d_in[8];
    const float* cbb = (const float*)d_in[9];
    const int* c_ids = (const int*)d_in[10];
    const int* p_ids = (const int*)d_in[11];
    const int* n_ids = (const int*)d_in[12];
    float* out = (float*)d_out;

    const int gene_blocks = 171;   // 6250 tiles of 32 rows -> 36-37 tiles/block
    const int cell_blocks = 341;   // 12500 tiles           -> 36-37 tiles/block
    dim3 grid(gene_blocks + cell_blocks);   // 512 = 2 blocks/CU, one round
    dim3 block(THREADS);
    hipLaunchKernelGGL(hetagg_kernel, grid, block, 0, stream,
                       gene_feat, cell_feat, gWf, gbf, gWb, gbb,
                       cWf, cbf, cWb, cbb, c_ids, p_ids, n_ids, out,
                       gene_blocks, cell_blocks);
}